// Round 1
// baseline (249.336 us; speedup 1.0000x reference)
//
#include <hip/hip_runtime.h>
#include <hip/hip_bf16.h>

// Problem: B=2, S=2048, EMB=1024, H=16, D=64.
// fp32 I/O; bf16 MFMA pipeline. V pre-transposed by QKV GEMM ([B,H,D,S]).
// Q pre-scaled by SCALE*log2(e) so attention softmax runs in exp2 domain.
#define BB   2
#define SS   2048
#define EMBD 1024
#define NH   16
#define HD   64
#define QSCALE 0.18033688011112042f  // 0.125 * log2(e)
#define NEG_BIG (-1e30f)

typedef __bf16 bf16;
typedef float  floatx4 __attribute__((ext_vector_type(4)));
typedef __bf16 bf16x4  __attribute__((ext_vector_type(4)));
typedef __bf16 bf16x8  __attribute__((ext_vector_type(8)));

typedef const __attribute__((address_space(1))) void* gas_ptr;
typedef __attribute__((address_space(3))) void*       las_ptr;

__device__ __forceinline__ void gl_lds16(const void* g, void* l) {
    __builtin_amdgcn_global_load_lds((gas_ptr)g, (las_ptr)l, 16, 0, 0);
}

__device__ __forceinline__ bf16x8 cvt8(const float* p) {
    bf16x8 o;
#pragma unroll
    for (int j = 0; j < 8; j++) o[j] = (bf16)p[j];
    return o;
}

// ---------------------------------------------------------------------------
// fp32 -> bf16 conversion for x tensors (4Mi els each) and W matrices (1Mi).
// ---------------------------------------------------------------------------
__global__ __launch_bounds__(256) void cvt_all(
    const float* __restrict__ xq, const float* __restrict__ xk,
    const float* __restrict__ xv, const float* __restrict__ Wq,
    const float* __restrict__ Wk, const float* __restrict__ Wv,
    const float* __restrict__ Wo, bf16* __restrict__ xqo,
    bf16* __restrict__ xko, bf16* __restrict__ xvo, bf16* __restrict__ Wqo,
    bf16* __restrict__ Wko, bf16* __restrict__ Wvo, bf16* __restrict__ Woo) {
    const int y = blockIdx.y;
    const float* src;
    bf16* dst;
    size_t n;
    const size_t NX = (size_t)BB * SS * EMBD;    // 4 Mi
    const size_t NW = (size_t)EMBD * EMBD;       // 1 Mi
    switch (y) {
        case 0: src = xq; dst = xqo; n = NX; break;
        case 1: src = xk; dst = xko; n = NX; break;
        case 2: src = xv; dst = xvo; n = NX; break;
        case 3: src = Wq; dst = Wqo; n = NW; break;
        case 4: src = Wk; dst = Wko; n = NW; break;
        case 5: src = Wv; dst = Wvo; n = NW; break;
        default: src = Wo; dst = Woo; n = NW; break;
    }
    const size_t stride = (size_t)gridDim.x * blockDim.x * 4;
    for (size_t i = ((size_t)blockIdx.x * blockDim.x + threadIdx.x) * 4;
         i < n; i += stride) {
        floatx4 v = *(const floatx4*)(src + i);
        bf16x4 o = {(bf16)v[0], (bf16)v[1], (bf16)v[2], (bf16)v[3]};
        *(bf16x4*)(dst + i) = o;
    }
}

// ---------------------------------------------------------------------------
// GEMM (unchanged): dynamic LDS, BK=64 staged as two packed 32-col halves,
// per-wave LDS repack epilogue.
// ---------------------------------------------------------------------------
extern __shared__ __align__(16) char smem[];

template <int MODE, int FM>
__device__ __forceinline__ void gemm_body(const bf16* __restrict__ A,
                                          const bf16* __restrict__ W,
                                          const float* __restrict__ bias,
                                          void* __restrict__ Ov,
                                          int mBase, int nBase, float oscale) {
    constexpr int BM = 32 * FM;
    constexpr int ABYTES = BM * 64 * 2;
    bf16* As = (bf16*)smem;
    bf16* Bs = (bf16*)(smem + ABYTES);

    const int t = threadIdx.x;
    const int l = t & 63, w = t >> 6;
    const int lm = l & 15, lq = l >> 4;
    const int K = 1024;
    const int wm = (w >> 1) * (16 * FM), wn = (w & 1) * 64;

    const floatx4 zero = {0.f, 0.f, 0.f, 0.f};
    floatx4 acc[FM][4];
#pragma unroll
    for (int i = 0; i < FM; i++)
#pragma unroll
        for (int j = 0; j < 4; j++) acc[i][j] = zero;

    for (int kb = 0; kb < K; kb += 64) {
        __syncthreads();
#pragma unroll
        for (int ia = 0; ia < FM; ia++) {
            int half = ia / (FM / 2 > 0 ? FM / 2 : 1);
            int rem  = (ia % (FM / 2 > 0 ? FM / 2 : 1)) * 256 + t;
            int row  = rem >> 2;
            int col  = half * 32 + (rem & 3) * 8;
            gl_lds16(A + (size_t)(mBase + row) * K + kb + col,
                     (char*)As + (ia * 256 + w * 64) * 16);
        }
#pragma unroll
        for (int i = 0; i < 4; i++) {
            int half = i >> 1;
            int rem  = (i & 1) * 256 + t;
            int row  = rem >> 2;
            int col  = half * 32 + (rem & 3) * 8;
            gl_lds16(W + (size_t)(nBase + row) * K + kb + col,
                     (char*)Bs + (i * 256 + w * 64) * 16);
        }
        __syncthreads();

#pragma unroll
        for (int half = 0; half < 2; half++) {
            const bf16* Ah = As + half * BM * 32;
            const bf16* Bh = Bs + half * 128 * 32;
            bf16x8 af[FM], bfv[4];
#pragma unroll
            for (int f = 0; f < FM; f++)
                af[f] = *(const bf16x8*)&Ah[(wm + f * 16 + lm) * 32 + lq * 8];
#pragma unroll
            for (int f = 0; f < 4; f++)
                bfv[f] = *(const bf16x8*)&Bh[(wn + f * 16 + lm) * 32 + lq * 8];
            if (MODE == 2) {
#pragma unroll
                for (int i = 0; i < 4; i++)
#pragma unroll
                    for (int j = 0; j < FM; j++)
                        acc[j][i] = __builtin_amdgcn_mfma_f32_16x16x32_bf16(
                            bfv[i], af[j], acc[j][i], 0, 0, 0);
            } else {
#pragma unroll
                for (int fm = 0; fm < FM; fm++)
#pragma unroll
                    for (int fn = 0; fn < 4; fn++)
                        acc[fm][fn] =
                            __builtin_amdgcn_mfma_f32_16x16x32_bf16(
                                af[fm], bfv[fn], acc[fm][fn], 0, 0, 0);
            }
        }
    }

    __syncthreads();
    float* rp = (float*)smem + w * (16 * 68);

    if (MODE != 2) {
        float bvv[4];
#pragma unroll
        for (int fn = 0; fn < 4; fn++)
            bvv[fn] = bias[nBase + wn + fn * 16 + lm];
#pragma unroll
        for (int fm = 0; fm < FM; fm++) {
#pragma unroll
            for (int fn = 0; fn < 4; fn++)
#pragma unroll
                for (int r = 0; r < 4; r++)
                    rp[(lq * 4 + r) * 68 + fn * 16 + lm] =
                        (acc[fm][fn][r] + bvv[fn]) * oscale;
            if (MODE == 0) {
                int row2 = l >> 3, col8 = l & 7;
                int h = (nBase + wn) >> 6;
#pragma unroll
                for (int p = 0; p < 2; p++) {
                    int row = p * 8 + row2;
                    int m = mBase + wm + fm * 16 + row;
                    int b = m >> 11, s = m & 2047;
                    bf16x8 o = cvt8(&rp[row * 68 + col8 * 8]);
                    *(bf16x8*)((bf16*)Ov +
                               (((size_t)(b * NH + h)) * SS + s) * HD +
                               col8 * 8) = o;
                }
            } else {
                int c4 = l & 15;
#pragma unroll
                for (int p = 0; p < 4; p++) {
                    int row = p * 4 + (l >> 4);
                    int m = mBase + wm + fm * 16 + row;
                    floatx4 o = *(const floatx4*)&rp[row * 68 + c4 * 4];
                    *(floatx4*)((float*)Ov + (size_t)m * EMBD + nBase + wn +
                                c4 * 4) = o;
                }
            }
        }
    } else {
        const int b = (mBase + wm) >> 11;
        const int sbase = (mBase + wm) & 2047;
#pragma unroll
        for (int i = 0; i < 4; i++) {
            float bv[4];
#pragma unroll
            for (int r = 0; r < 4; r++)
                bv[r] = bias[nBase + wn + i * 16 + lq * 4 + r];
#pragma unroll
            for (int j = 0; j < FM; j++)
#pragma unroll
                for (int r = 0; r < 4; r++)
                    rp[(lq * 4 + r) * 68 + j * 16 + lm] =
                        acc[j][i][r] + bv[r];
            int row2 = l >> 3, col8 = l & 7;
#pragma unroll
            for (int p = 0; p < 2; p++) {
                int row = p * 8 + row2;
                int n = nBase + wn + i * 16 + row;
                int h = n >> 6, d = n & 63;
                bf16x8 o = cvt8(&rp[row * 68 + col8 * 8]);
                *(bf16x8*)((bf16*)Ov +
                           ((size_t)(b * NH + h) * HD + d) * SS + sbase +
                           col8 * 8) = o;
            }
        }
    }
}

__global__ __launch_bounds__(256, 4) void gemm_qkv(
    const bf16* __restrict__ xq, const bf16* __restrict__ xk,
    const bf16* __restrict__ xv, const bf16* __restrict__ Wq,
    const bf16* __restrict__ Wk, const bf16* __restrict__ Wv,
    const float* __restrict__ bq, const float* __restrict__ bk,
    const float* __restrict__ bv, bf16* __restrict__ Qo,
    bf16* __restrict__ Ko, bf16* __restrict__ Vo) {
    const int z = blockIdx.z;
    const int mB = blockIdx.x * 128, nB = blockIdx.y * 128;
    if (z == 0)
        gemm_body<0, 4>(xq, Wq, bq, Qo, mB, nB, QSCALE);
    else if (z == 1)
        gemm_body<0, 4>(xk, Wk, bk, Ko, mB, nB, 1.0f);
    else
        gemm_body<2, 4>(xv, Wv, bv, Vo, mB, nB, 1.0f);
}

__global__ __launch_bounds__(256, 4) void gemm_out(
    const bf16* __restrict__ A, const bf16* __restrict__ W,
    const float* __restrict__ bias, float* __restrict__ O) {
    gemm_body<1, 2>(A, W, bias, O, blockIdx.x * 64, blockIdx.y * 128, 1.0f);
}

// ---------------------------------------------------------------------------
// Flash attention, KT=128, v2:
//  - Unpadded XOR-swizzled LDS tiles: Ks[128][64] (16 KB), VT[64][128]
//    (16 KB), Ps per-wave 64-key half [4][16][64] (8 KB) -> 40 KB total ->
//    4 blocks/CU (was 53 KB / 3 blocks). Swizzle: 16B slot ^= (row&7);
//    balanced banks on both write and read sides.
//  - Ps consumed in two 64-key passes (same-wave DS ordering; no barrier).
//  - Grid 1024 = 256 CU x 4: fully co-resident; qt map gives each CU the
//    set {j, 15-j, 16+j, 31-j} -> constant 34 chunks/CU.
//  - Tree max / 4-accum sum to shorten the softmax dependency chain.
// ---------------------------------------------------------------------------
__global__ __launch_bounds__(256, 4) void attn_fwd(
    const bf16* __restrict__ Qg, const bf16* __restrict__ Kg,
    const bf16* __restrict__ Vtg, bf16* __restrict__ Oatt) {
    __shared__ __align__(16) bf16 Ks[128 * 64];    // [key][d], swizzled
    __shared__ __align__(16) bf16 VT[64 * 128];    // [d][key], swizzled
    __shared__ __align__(16) bf16 Ps[4][16 * 64];  // per-wave P half, swz

    const int t = threadIdx.x;
    const int l = t & 63, w = t >> 6;
    const int lm = l & 15, lq = l >> 4;
    const int m7 = lm & 7;
    const int x = blockIdx.x;
    const int i5 = x >> 5;                      // 0..31
    const int gq = i5 >> 3, jq = i5 & 7;
    const int qt = (gq == 0) ? jq
                 : (gq == 1) ? 15 - jq
                 : (gq == 2) ? 16 + jq
                             : 31 - jq;        // balanced bijection
    const int bh = (((x >> 3) & 3) << 3) | (x & 7);  // XCD-pinned head
    const int nch = (qt >> 1) + 1;             // 128-key chunks
    const size_t kbase = (size_t)bh * SS * HD;
    const size_t vbase = (size_t)bh * HD * SS;
    const int b = bh >> 4, h = bh & 15;
    const floatx4 zero = {0.f, 0.f, 0.f, 0.f};

    bf16x8 qa0, qa1;
    {
        const bf16* qp =
            Qg + kbase + (size_t)(qt * 64 + w * 16 + lm) * HD + lq * 8;
        qa0 = *(const bf16x8*)qp;
        qa1 = *(const bf16x8*)(qp + 32);
    }

    float m_i = NEG_BIG, l_i = 0.f;            // stats for q = lm (this wave)
    floatx4 od[4];
#pragma unroll
    for (int dt = 0; dt < 4; dt++) od[dt] = zero;

    const int qglob = qt * 64 + w * 16 + lm;

    // Prefetch chunk 0: K rows 0..127, V^T keys 0..127.
    bf16x8 kreg[4], vreg[4];
#pragma unroll
    for (int i = 0; i < 4; i++) {
        int idx = i * 256 + t;                 // 0..1023
        int rowK = idx >> 3, colK = (idx & 7) * 8;
        kreg[i] = *(const bf16x8*)(Kg + kbase + (size_t)rowK * HD + colK);
        int dV = idx >> 4, keyb = (idx & 15) * 8;
        vreg[i] = *(const bf16x8*)(Vtg + vbase + (size_t)dV * SS + keyb);
    }

    for (int kt = 0; kt < nch; ++kt) {
        __syncthreads();
#pragma unroll
        for (int i = 0; i < 4; i++) {
            int idx = i * 256 + t;
            int rowK = idx >> 3, c16 = idx & 7;
            *(bf16x8*)&Ks[rowK * 64 + ((c16 ^ (rowK & 7)) << 3)] = kreg[i];
            int dV = idx >> 4, k16 = idx & 15;
            *(bf16x8*)&VT[dV * 128 +
                          (((k16 & 8) | ((k16 ^ dV) & 7)) << 3)] = vreg[i];
        }
        __syncthreads();
        if (kt < nch - 1) {
#pragma unroll
            for (int i = 0; i < 4; i++) {
                int idx = i * 256 + t;
                int rowK = idx >> 3, colK = (idx & 7) * 8;
                kreg[i] = *(const bf16x8*)(
                    Kg + kbase + (size_t)((kt + 1) * 128 + rowK) * HD + colK);
                int dV = idx >> 4, keyb = (idx & 15) * 8;
                vreg[i] = *(const bf16x8*)(
                    Vtg + vbase + (size_t)dV * SS + (kt + 1) * 128 + keyb);
            }
        }

        // S^T[key][q], 8 subtiles of 16 keys (128 total)
        floatx4 sc[8];
#pragma unroll
        for (int j0 = 0; j0 < 8; j0++) {
            int rowK = j0 * 16 + lm;
            bf16x8 k0 = *(const bf16x8*)&Ks[rowK * 64 + ((lq ^ m7) << 3)];
            bf16x8 k1 =
                *(const bf16x8*)&Ks[rowK * 64 + (((4 + lq) ^ m7) << 3)];
            floatx4 z = zero;
            z = __builtin_amdgcn_mfma_f32_16x16x32_bf16(k0, qa0, z, 0, 0, 0);
            z = __builtin_amdgcn_mfma_f32_16x16x32_bf16(k1, qa1, z, 0, 0, 0);
            sc[j0] = z;
        }
        if (kt == nch - 1) {  // causal mask: diagonal + 64-key overhang
#pragma unroll
            for (int j0 = 0; j0 < 8; j0++)
#pragma unroll
                for (int r = 0; r < 4; r++) {
                    int key = kt * 128 + j0 * 16 + lq * 4 + r;
                    if (key > qglob) sc[j0][r] = NEG_BIG;
                }
        }
        // Online softmax (exp2 domain); all 32 regs belong to q = lm.
        // Tree max: 4-wide partials, then combine (short dep chain).
        float m4[4];
#pragma unroll
        for (int a = 0; a < 4; a++) {
            float u0 = fmaxf(fmaxf(sc[a][0], sc[a][1]),
                             fmaxf(sc[a][2], sc[a][3]));
            float u1 = fmaxf(fmaxf(sc[a + 4][0], sc[a + 4][1]),
                             fmaxf(sc[a + 4][2], sc[a + 4][3]));
            m4[a] = fmaxf(u0, u1);
        }
        float mt = fmaxf(fmaxf(m4[0], m4[1]), fmaxf(m4[2], m4[3]));
        mt = fmaxf(mt, __shfl_xor(mt, 16));
        mt = fmaxf(mt, __shfl_xor(mt, 32));
        float mnew = fmaxf(m_i, mt);
        float alpha = __builtin_amdgcn_exp2f(m_i - mnew);
        m_i = mnew;
        float psa0 = 0.f, psa1 = 0.f, psa2 = 0.f, psa3 = 0.f;
#pragma unroll
        for (int j0 = 0; j0 < 8; j0++) {
            float p0 = __builtin_amdgcn_exp2f(sc[j0][0] - mnew);
            float p1 = __builtin_amdgcn_exp2f(sc[j0][1] - mnew);
            float p2 = __builtin_amdgcn_exp2f(sc[j0][2] - mnew);
            float p3 = __builtin_amdgcn_exp2f(sc[j0][3] - mnew);
            sc[j0][0] = p0; sc[j0][1] = p1;
            sc[j0][2] = p2; sc[j0][3] = p3;
            psa0 += p0; psa1 += p1; psa2 += p2; psa3 += p3;
        }
        float ps = (psa0 + psa1) + (psa2 + psa3);
        ps += __shfl_xor(ps, 16);
        ps += __shfl_xor(ps, 32);
        l_i = l_i * alpha + ps;
        float a0 = __shfl(alpha, lq * 4 + 0);
        float a1 = __shfl(alpha, lq * 4 + 1);
        float a2 = __shfl(alpha, lq * 4 + 2);
        float a3 = __shfl(alpha, lq * 4 + 3);
#pragma unroll
        for (int dt = 0; dt < 4; dt++) {
            od[dt][0] *= a0;
            od[dt][1] *= a1;
            od[dt][2] *= a2;
            od[dt][3] *= a3;
        }
        // PV over 128 keys in two 64-key halves through the 8 KB Ps buffer.
        // Same-wave DS program order guarantees h0 reads precede h1 writes.
#pragma unroll
        for (int hv = 0; hv < 2; hv++) {
#pragma unroll
            for (int j0l = 0; j0l < 4; j0l++) {
                floatx4 s4 = sc[hv * 4 + j0l];
                bf16x4 pk = {(bf16)s4[0], (bf16)s4[1], (bf16)s4[2],
                             (bf16)s4[3]};
                *(bf16x4*)&Ps[w][lm * 64 +
                                 ((j0l * 16 + lq * 4) ^ (m7 * 8))] = pk;
            }
            bf16x8 pa0 =
                *(const bf16x8*)&Ps[w][lm * 64 + ((lq * 8) ^ (m7 * 8))];
            bf16x8 pa1 =
                *(const bf16x8*)&Ps[w][lm * 64 + ((32 + lq * 8) ^ (m7 * 8))];
#pragma unroll
            for (int dt = 0; dt < 4; dt++) {
                int rowD = dt * 16 + lm;
                int sl0 = hv * 8 + lq;          // 16B slot of key step hv*2
                int sl1 = sl0 + 4;              // key step hv*2 + 1
                bf16x8 v0 = *(const bf16x8*)&VT[
                    rowD * 128 + (((sl0 & 8) | ((sl0 ^ m7) & 7)) << 3)];
                od[dt] = __builtin_amdgcn_mfma_f32_16x16x32_bf16(pa0, v0,
                                                                 od[dt], 0, 0,
                                                                 0);
                bf16x8 v1 = *(const bf16x8*)&VT[
                    rowD * 128 + (((sl1 & 8) | ((sl1 ^ m7) & 7)) << 3)];
                od[dt] = __builtin_amdgcn_mfma_f32_16x16x32_bf16(pa1, v1,
                                                                 od[dt], 0, 0,
                                                                 0);
            }
        }
    }

    float linv = 1.0f / l_i;
    float lr0 = __shfl(linv, lq * 4 + 0);
    float lr1 = __shfl(linv, lq * 4 + 1);
    float lr2 = __shfl(linv, lq * 4 + 2);
    float lr3 = __shfl(linv, lq * 4 + 3);
    float lr[4] = {lr0, lr1, lr2, lr3};
#pragma unroll
    for (int dt = 0; dt < 4; dt++) {
#pragma unroll
        for (int r = 0; r < 4; r++) {
            int s = qt * 64 + w * 16 + lq * 4 + r;
            float v = od[dt][r] * lr[r];
            Oatt[((size_t)(b * SS + s)) * EMBD + h * HD + dt * 16 + lm] =
                (bf16)v;
        }
    }
}

// ---------------------------------------------------------------------------
extern "C" void kernel_launch(void* const* d_in, const int* in_sizes, int n_in,
                              void* d_out, int out_size, void* d_ws,
                              size_t ws_size, hipStream_t stream) {
    const float* xq = (const float*)d_in[0];
    const float* xk = (const float*)d_in[1];
    const float* xv = (const float*)d_in[2];
    // d_in[3] = causal mask — hard-coded
    const float* Wq = (const float*)d_in[4];
    const float* bq = (const float*)d_in[5];
    const float* Wk = (const float*)d_in[6];
    const float* bk = (const float*)d_in[7];
    const float* Wv = (const float*)d_in[8];
    const float* bv = (const float*)d_in[9];
    const float* Wo = (const float*)d_in[10];
    const float* bo = (const float*)d_in[11];
    float* out = (float*)d_out;

    const size_t NX = (size_t)BB * SS * EMBD;
    const size_t NW = (size_t)EMBD * EMBD;
    bf16* Qw  = (bf16*)d_ws;        // [B,H,S,D], pre-scaled
    bf16* Kw  = Qw + NX;            // [B,H,S,D]
    bf16* Vw  = Kw + NX;            // [B,H,D,S]
    bf16* Aw  = Vw + NX;            // [B,S,E]
    bf16* xqb = Aw + NX;
    bf16* xkb = xqb + NX;
    bf16* xvb = xkb + NX;
    bf16* Wqb = xvb + NX;
    bf16* Wkb = Wqb + NW;
    bf16* Wvb = Wkb + NW;
    bf16* Wob = Wvb + NW;

    cvt_all<<<dim3(1024, 7), 256, 0, stream>>>(xq, xk, xv, Wq, Wk, Wv, Wo,
                                               xqb, xkb, xvb, Wqb, Wkb, Wvb,
                                               Wob);
    gemm_qkv<<<dim3(32, 8, 3), 256, 32768, stream>>>(
        xqb, xkb, xvb, Wqb, Wkb, Wvb, bq, bk, bv, Qw, Kw, Vw);
    attn_fwd<<<dim3(1024), 256, 0, stream>>>(Qw, Kw, Vw, Aw);
    gemm_out<<<dim3(64, 8), 256, 24576, stream>>>(Aw, Wob, bo, out);
}

// Round 2
// 229.189 us; speedup vs baseline: 1.0879x; 1.0879x over previous
//
#include <hip/hip_runtime.h>
#include <hip/hip_bf16.h>

// Problem: B=2, S=2048, EMB=1024, H=16, D=64.
// fp32 I/O; bf16 MFMA pipeline. V pre-transposed by QKV GEMM ([B,H,D,S]).
// Q pre-scaled by SCALE*log2(e) so attention softmax runs in exp2 domain.
#define BB   2
#define SS   2048
#define EMBD 1024
#define NH   16
#define HD   64
#define QSCALE 0.18033688011112042f  // 0.125 * log2(e)
#define NEG_BIG (-1e30f)

typedef __bf16 bf16;
typedef float  floatx4 __attribute__((ext_vector_type(4)));
typedef __bf16 bf16x4  __attribute__((ext_vector_type(4)));
typedef __bf16 bf16x8  __attribute__((ext_vector_type(8)));

typedef const __attribute__((address_space(1))) void* gas_ptr;
typedef __attribute__((address_space(3))) void*       las_ptr;

__device__ __forceinline__ void gl_lds16(const void* g, void* l) {
    __builtin_amdgcn_global_load_lds((gas_ptr)g, (las_ptr)l, 16, 0, 0);
}

__device__ __forceinline__ bf16x8 cvt8(const float* p) {
    bf16x8 o;
#pragma unroll
    for (int j = 0; j < 8; j++) o[j] = (bf16)p[j];
    return o;
}

// ---------------------------------------------------------------------------
// fp32 -> bf16 conversion for x tensors (4Mi els each) and W matrices (1Mi).
// ---------------------------------------------------------------------------
__global__ __launch_bounds__(256) void cvt_all(
    const float* __restrict__ xq, const float* __restrict__ xk,
    const float* __restrict__ xv, const float* __restrict__ Wq,
    const float* __restrict__ Wk, const float* __restrict__ Wv,
    const float* __restrict__ Wo, bf16* __restrict__ xqo,
    bf16* __restrict__ xko, bf16* __restrict__ xvo, bf16* __restrict__ Wqo,
    bf16* __restrict__ Wko, bf16* __restrict__ Wvo, bf16* __restrict__ Woo) {
    const int y = blockIdx.y;
    const float* src;
    bf16* dst;
    size_t n;
    const size_t NX = (size_t)BB * SS * EMBD;    // 4 Mi
    const size_t NW = (size_t)EMBD * EMBD;       // 1 Mi
    switch (y) {
        case 0: src = xq; dst = xqo; n = NX; break;
        case 1: src = xk; dst = xko; n = NX; break;
        case 2: src = xv; dst = xvo; n = NX; break;
        case 3: src = Wq; dst = Wqo; n = NW; break;
        case 4: src = Wk; dst = Wko; n = NW; break;
        case 5: src = Wv; dst = Wvo; n = NW; break;
        default: src = Wo; dst = Woo; n = NW; break;
    }
    const size_t stride = (size_t)gridDim.x * blockDim.x * 4;
    for (size_t i = ((size_t)blockIdx.x * blockDim.x + threadIdx.x) * 4;
         i < n; i += stride) {
        floatx4 v = *(const floatx4*)(src + i);
        bf16x4 o = {(bf16)v[0], (bf16)v[1], (bf16)v[2], (bf16)v[3]};
        *(bf16x4*)(dst + i) = o;
    }
}

// ---------------------------------------------------------------------------
// GEMM (unchanged): dynamic LDS, BK=64 staged as two packed 32-col halves,
// per-wave LDS repack epilogue.
// ---------------------------------------------------------------------------
extern __shared__ __align__(16) char smem[];

template <int MODE, int FM>
__device__ __forceinline__ void gemm_body(const bf16* __restrict__ A,
                                          const bf16* __restrict__ W,
                                          const float* __restrict__ bias,
                                          void* __restrict__ Ov,
                                          int mBase, int nBase, float oscale) {
    constexpr int BM = 32 * FM;
    constexpr int ABYTES = BM * 64 * 2;
    bf16* As = (bf16*)smem;
    bf16* Bs = (bf16*)(smem + ABYTES);

    const int t = threadIdx.x;
    const int l = t & 63, w = t >> 6;
    const int lm = l & 15, lq = l >> 4;
    const int K = 1024;
    const int wm = (w >> 1) * (16 * FM), wn = (w & 1) * 64;

    const floatx4 zero = {0.f, 0.f, 0.f, 0.f};
    floatx4 acc[FM][4];
#pragma unroll
    for (int i = 0; i < FM; i++)
#pragma unroll
        for (int j = 0; j < 4; j++) acc[i][j] = zero;

    for (int kb = 0; kb < K; kb += 64) {
        __syncthreads();
#pragma unroll
        for (int ia = 0; ia < FM; ia++) {
            int half = ia / (FM / 2 > 0 ? FM / 2 : 1);
            int rem  = (ia % (FM / 2 > 0 ? FM / 2 : 1)) * 256 + t;
            int row  = rem >> 2;
            int col  = half * 32 + (rem & 3) * 8;
            gl_lds16(A + (size_t)(mBase + row) * K + kb + col,
                     (char*)As + (ia * 256 + w * 64) * 16);
        }
#pragma unroll
        for (int i = 0; i < 4; i++) {
            int half = i >> 1;
            int rem  = (i & 1) * 256 + t;
            int row  = rem >> 2;
            int col  = half * 32 + (rem & 3) * 8;
            gl_lds16(W + (size_t)(nBase + row) * K + kb + col,
                     (char*)Bs + (i * 256 + w * 64) * 16);
        }
        __syncthreads();

#pragma unroll
        for (int half = 0; half < 2; half++) {
            const bf16* Ah = As + half * BM * 32;
            const bf16* Bh = Bs + half * 128 * 32;
            bf16x8 af[FM], bfv[4];
#pragma unroll
            for (int f = 0; f < FM; f++)
                af[f] = *(const bf16x8*)&Ah[(wm + f * 16 + lm) * 32 + lq * 8];
#pragma unroll
            for (int f = 0; f < 4; f++)
                bfv[f] = *(const bf16x8*)&Bh[(wn + f * 16 + lm) * 32 + lq * 8];
            if (MODE == 2) {
#pragma unroll
                for (int i = 0; i < 4; i++)
#pragma unroll
                    for (int j = 0; j < FM; j++)
                        acc[j][i] = __builtin_amdgcn_mfma_f32_16x16x32_bf16(
                            bfv[i], af[j], acc[j][i], 0, 0, 0);
            } else {
#pragma unroll
                for (int fm = 0; fm < FM; fm++)
#pragma unroll
                    for (int fn = 0; fn < 4; fn++)
                        acc[fm][fn] =
                            __builtin_amdgcn_mfma_f32_16x16x32_bf16(
                                af[fm], bfv[fn], acc[fm][fn], 0, 0, 0);
            }
        }
    }

    __syncthreads();
    float* rp = (float*)smem + w * (16 * 68);

    if (MODE != 2) {
        float bvv[4];
#pragma unroll
        for (int fn = 0; fn < 4; fn++)
            bvv[fn] = bias[nBase + wn + fn * 16 + lm];
#pragma unroll
        for (int fm = 0; fm < FM; fm++) {
#pragma unroll
            for (int fn = 0; fn < 4; fn++)
#pragma unroll
                for (int r = 0; r < 4; r++)
                    rp[(lq * 4 + r) * 68 + fn * 16 + lm] =
                        (acc[fm][fn][r] + bvv[fn]) * oscale;
            if (MODE == 0) {
                int row2 = l >> 3, col8 = l & 7;
                int h = (nBase + wn) >> 6;
#pragma unroll
                for (int p = 0; p < 2; p++) {
                    int row = p * 8 + row2;
                    int m = mBase + wm + fm * 16 + row;
                    int b = m >> 11, s = m & 2047;
                    bf16x8 o = cvt8(&rp[row * 68 + col8 * 8]);
                    *(bf16x8*)((bf16*)Ov +
                               (((size_t)(b * NH + h)) * SS + s) * HD +
                               col8 * 8) = o;
                }
            } else {
                int c4 = l & 15;
#pragma unroll
                for (int p = 0; p < 4; p++) {
                    int row = p * 4 + (l >> 4);
                    int m = mBase + wm + fm * 16 + row;
                    floatx4 o = *(const floatx4*)&rp[row * 68 + c4 * 4];
                    *(floatx4*)((float*)Ov + (size_t)m * EMBD + nBase + wn +
                                c4 * 4) = o;
                }
            }
        }
    } else {
        const int b = (mBase + wm) >> 11;
        const int sbase = (mBase + wm) & 2047;
#pragma unroll
        for (int i = 0; i < 4; i++) {
            float bv[4];
#pragma unroll
            for (int r = 0; r < 4; r++)
                bv[r] = bias[nBase + wn + i * 16 + lq * 4 + r];
#pragma unroll
            for (int j = 0; j < FM; j++)
#pragma unroll
                for (int r = 0; r < 4; r++)
                    rp[(lq * 4 + r) * 68 + j * 16 + lm] =
                        acc[j][i][r] + bv[r];
            int row2 = l >> 3, col8 = l & 7;
#pragma unroll
            for (int p = 0; p < 2; p++) {
                int row = p * 8 + row2;
                int n = nBase + wn + i * 16 + row;
                int h = n >> 6, d = n & 63;
                bf16x8 o = cvt8(&rp[row * 68 + col8 * 8]);
                *(bf16x8*)((bf16*)Ov +
                           ((size_t)(b * NH + h) * HD + d) * SS + sbase +
                           col8 * 8) = o;
            }
        }
    }
}

__global__ __launch_bounds__(256, 4) void gemm_qkv(
    const bf16* __restrict__ xq, const bf16* __restrict__ xk,
    const bf16* __restrict__ xv, const bf16* __restrict__ Wq,
    const bf16* __restrict__ Wk, const bf16* __restrict__ Wv,
    const float* __restrict__ bq, const float* __restrict__ bk,
    const float* __restrict__ bv, bf16* __restrict__ Qo,
    bf16* __restrict__ Ko, bf16* __restrict__ Vo) {
    const int z = blockIdx.z;
    const int mB = blockIdx.x * 128, nB = blockIdx.y * 128;
    if (z == 0)
        gemm_body<0, 4>(xq, Wq, bq, Qo, mB, nB, QSCALE);
    else if (z == 1)
        gemm_body<0, 4>(xk, Wk, bk, Ko, mB, nB, 1.0f);
    else
        gemm_body<2, 4>(xv, Wv, bv, Vo, mB, nB, 1.0f);
}

__global__ __launch_bounds__(256, 4) void gemm_out(
    const bf16* __restrict__ A, const bf16* __restrict__ W,
    const float* __restrict__ bias, float* __restrict__ O) {
    gemm_body<1, 2>(A, W, bias, O, blockIdx.x * 64, blockIdx.y * 128, 1.0f);
}

// ---------------------------------------------------------------------------
// Flash attention, KT=128, v3:
//  - v2 structure kept: unpadded XOR-swizzled LDS tiles Ks[128][64] (16 KB),
//    VT[64][128] (16 KB), Ps per-wave 64-key half [4][16][64] (8 KB) ->
//    40 KB total; balanced qt bijection; tree max / 4-accum softmax sum.
//  - FIX vs v2: __launch_bounds__(256, 3) not (256, 4). The (256,4) clamp
//    forced VGPR_Count to 64 against a ~108-reg live set -> scratch spills
//    (WRITE_SIZE 98 MB vs 8 MB of real output, FETCH 43 MB). At (256,3)
//    the allocator used 84 VGPRs (no spill); <=128 VGPR still permits
//    4 waves/SIMD so the 40 KB LDS still allows 4 blocks/CU.
// ---------------------------------------------------------------------------
__global__ __launch_bounds__(256, 3) void attn_fwd(
    const bf16* __restrict__ Qg, const bf16* __restrict__ Kg,
    const bf16* __restrict__ Vtg, bf16* __restrict__ Oatt) {
    __shared__ __align__(16) bf16 Ks[128 * 64];    // [key][d], swizzled
    __shared__ __align__(16) bf16 VT[64 * 128];    // [d][key], swizzled
    __shared__ __align__(16) bf16 Ps[4][16 * 64];  // per-wave P half, swz

    const int t = threadIdx.x;
    const int l = t & 63, w = t >> 6;
    const int lm = l & 15, lq = l >> 4;
    const int m7 = lm & 7;
    const int x = blockIdx.x;
    const int i5 = x >> 5;                      // 0..31
    const int gq = i5 >> 3, jq = i5 & 7;
    const int qt = (gq == 0) ? jq
                 : (gq == 1) ? 15 - jq
                 : (gq == 2) ? 16 + jq
                             : 31 - jq;        // balanced bijection
    const int bh = (((x >> 3) & 3) << 3) | (x & 7);  // XCD-pinned head
    const int nch = (qt >> 1) + 1;             // 128-key chunks
    const size_t kbase = (size_t)bh * SS * HD;
    const size_t vbase = (size_t)bh * HD * SS;
    const int b = bh >> 4, h = bh & 15;
    const floatx4 zero = {0.f, 0.f, 0.f, 0.f};

    bf16x8 qa0, qa1;
    {
        const bf16* qp =
            Qg + kbase + (size_t)(qt * 64 + w * 16 + lm) * HD + lq * 8;
        qa0 = *(const bf16x8*)qp;
        qa1 = *(const bf16x8*)(qp + 32);
    }

    float m_i = NEG_BIG, l_i = 0.f;            // stats for q = lm (this wave)
    floatx4 od[4];
#pragma unroll
    for (int dt = 0; dt < 4; dt++) od[dt] = zero;

    const int qglob = qt * 64 + w * 16 + lm;

    // Prefetch chunk 0: K rows 0..127, V^T keys 0..127.
    bf16x8 kreg[4], vreg[4];
#pragma unroll
    for (int i = 0; i < 4; i++) {
        int idx = i * 256 + t;                 // 0..1023
        int rowK = idx >> 3, colK = (idx & 7) * 8;
        kreg[i] = *(const bf16x8*)(Kg + kbase + (size_t)rowK * HD + colK);
        int dV = idx >> 4, keyb = (idx & 15) * 8;
        vreg[i] = *(const bf16x8*)(Vtg + vbase + (size_t)dV * SS + keyb);
    }

    for (int kt = 0; kt < nch; ++kt) {
        __syncthreads();
#pragma unroll
        for (int i = 0; i < 4; i++) {
            int idx = i * 256 + t;
            int rowK = idx >> 3, c16 = idx & 7;
            *(bf16x8*)&Ks[rowK * 64 + ((c16 ^ (rowK & 7)) << 3)] = kreg[i];
            int dV = idx >> 4, k16 = idx & 15;
            *(bf16x8*)&VT[dV * 128 +
                          (((k16 & 8) | ((k16 ^ dV) & 7)) << 3)] = vreg[i];
        }
        __syncthreads();
        if (kt < nch - 1) {
#pragma unroll
            for (int i = 0; i < 4; i++) {
                int idx = i * 256 + t;
                int rowK = idx >> 3, colK = (idx & 7) * 8;
                kreg[i] = *(const bf16x8*)(
                    Kg + kbase + (size_t)((kt + 1) * 128 + rowK) * HD + colK);
                int dV = idx >> 4, keyb = (idx & 15) * 8;
                vreg[i] = *(const bf16x8*)(
                    Vtg + vbase + (size_t)dV * SS + (kt + 1) * 128 + keyb);
            }
        }

        // S^T[key][q], 8 subtiles of 16 keys (128 total)
        floatx4 sc[8];
#pragma unroll
        for (int j0 = 0; j0 < 8; j0++) {
            int rowK = j0 * 16 + lm;
            bf16x8 k0 = *(const bf16x8*)&Ks[rowK * 64 + ((lq ^ m7) << 3)];
            bf16x8 k1 =
                *(const bf16x8*)&Ks[rowK * 64 + (((4 + lq) ^ m7) << 3)];
            floatx4 z = zero;
            z = __builtin_amdgcn_mfma_f32_16x16x32_bf16(k0, qa0, z, 0, 0, 0);
            z = __builtin_amdgcn_mfma_f32_16x16x32_bf16(k1, qa1, z, 0, 0, 0);
            sc[j0] = z;
        }
        if (kt == nch - 1) {  // causal mask: diagonal + 64-key overhang
#pragma unroll
            for (int j0 = 0; j0 < 8; j0++)
#pragma unroll
                for (int r = 0; r < 4; r++) {
                    int key = kt * 128 + j0 * 16 + lq * 4 + r;
                    if (key > qglob) sc[j0][r] = NEG_BIG;
                }
        }
        // Online softmax (exp2 domain); all 32 regs belong to q = lm.
        // Tree max: 4-wide partials, then combine (short dep chain).
        float m4[4];
#pragma unroll
        for (int a = 0; a < 4; a++) {
            float u0 = fmaxf(fmaxf(sc[a][0], sc[a][1]),
                             fmaxf(sc[a][2], sc[a][3]));
            float u1 = fmaxf(fmaxf(sc[a + 4][0], sc[a + 4][1]),
                             fmaxf(sc[a + 4][2], sc[a + 4][3]));
            m4[a] = fmaxf(u0, u1);
        }
        float mt = fmaxf(fmaxf(m4[0], m4[1]), fmaxf(m4[2], m4[3]));
        mt = fmaxf(mt, __shfl_xor(mt, 16));
        mt = fmaxf(mt, __shfl_xor(mt, 32));
        float mnew = fmaxf(m_i, mt);
        float alpha = __builtin_amdgcn_exp2f(m_i - mnew);
        m_i = mnew;
        float psa0 = 0.f, psa1 = 0.f, psa2 = 0.f, psa3 = 0.f;
#pragma unroll
        for (int j0 = 0; j0 < 8; j0++) {
            float p0 = __builtin_amdgcn_exp2f(sc[j0][0] - mnew);
            float p1 = __builtin_amdgcn_exp2f(sc[j0][1] - mnew);
            float p2 = __builtin_amdgcn_exp2f(sc[j0][2] - mnew);
            float p3 = __builtin_amdgcn_exp2f(sc[j0][3] - mnew);
            sc[j0][0] = p0; sc[j0][1] = p1;
            sc[j0][2] = p2; sc[j0][3] = p3;
            psa0 += p0; psa1 += p1; psa2 += p2; psa3 += p3;
        }
        float ps = (psa0 + psa1) + (psa2 + psa3);
        ps += __shfl_xor(ps, 16);
        ps += __shfl_xor(ps, 32);
        l_i = l_i * alpha + ps;
        float a0 = __shfl(alpha, lq * 4 + 0);
        float a1 = __shfl(alpha, lq * 4 + 1);
        float a2 = __shfl(alpha, lq * 4 + 2);
        float a3 = __shfl(alpha, lq * 4 + 3);
#pragma unroll
        for (int dt = 0; dt < 4; dt++) {
            od[dt][0] *= a0;
            od[dt][1] *= a1;
            od[dt][2] *= a2;
            od[dt][3] *= a3;
        }
        // PV over 128 keys in two 64-key halves through the 8 KB Ps buffer.
        // Same-wave DS program order guarantees h0 reads precede h1 writes.
#pragma unroll
        for (int hv = 0; hv < 2; hv++) {
#pragma unroll
            for (int j0l = 0; j0l < 4; j0l++) {
                floatx4 s4 = sc[hv * 4 + j0l];
                bf16x4 pk = {(bf16)s4[0], (bf16)s4[1], (bf16)s4[2],
                             (bf16)s4[3]};
                *(bf16x4*)&Ps[w][lm * 64 +
                                 ((j0l * 16 + lq * 4) ^ (m7 * 8))] = pk;
            }
            bf16x8 pa0 =
                *(const bf16x8*)&Ps[w][lm * 64 + ((lq * 8) ^ (m7 * 8))];
            bf16x8 pa1 =
                *(const bf16x8*)&Ps[w][lm * 64 + ((32 + lq * 8) ^ (m7 * 8))];
#pragma unroll
            for (int dt = 0; dt < 4; dt++) {
                int rowD = dt * 16 + lm;
                int sl0 = hv * 8 + lq;          // 16B slot of key step hv*2
                int sl1 = sl0 + 4;              // key step hv*2 + 1
                bf16x8 v0 = *(const bf16x8*)&VT[
                    rowD * 128 + (((sl0 & 8) | ((sl0 ^ m7) & 7)) << 3)];
                od[dt] = __builtin_amdgcn_mfma_f32_16x16x32_bf16(pa0, v0,
                                                                 od[dt], 0, 0,
                                                                 0);
                bf16x8 v1 = *(const bf16x8*)&VT[
                    rowD * 128 + (((sl1 & 8) | ((sl1 ^ m7) & 7)) << 3)];
                od[dt] = __builtin_amdgcn_mfma_f32_16x16x32_bf16(pa1, v1,
                                                                 od[dt], 0, 0,
                                                                 0);
            }
        }
    }

    float linv = 1.0f / l_i;
    float lr0 = __shfl(linv, lq * 4 + 0);
    float lr1 = __shfl(linv, lq * 4 + 1);
    float lr2 = __shfl(linv, lq * 4 + 2);
    float lr3 = __shfl(linv, lq * 4 + 3);
    float lr[4] = {lr0, lr1, lr2, lr3};
#pragma unroll
    for (int dt = 0; dt < 4; dt++) {
#pragma unroll
        for (int r = 0; r < 4; r++) {
            int s = qt * 64 + w * 16 + lq * 4 + r;
            float v = od[dt][r] * lr[r];
            Oatt[((size_t)(b * SS + s)) * EMBD + h * HD + dt * 16 + lm] =
                (bf16)v;
        }
    }
}

// ---------------------------------------------------------------------------
extern "C" void kernel_launch(void* const* d_in, const int* in_sizes, int n_in,
                              void* d_out, int out_size, void* d_ws,
                              size_t ws_size, hipStream_t stream) {
    const float* xq = (const float*)d_in[0];
    const float* xk = (const float*)d_in[1];
    const float* xv = (const float*)d_in[2];
    // d_in[3] = causal mask — hard-coded
    const float* Wq = (const float*)d_in[4];
    const float* bq = (const float*)d_in[5];
    const float* Wk = (const float*)d_in[6];
    const float* bk = (const float*)d_in[7];
    const float* Wv = (const float*)d_in[8];
    const float* bv = (const float*)d_in[9];
    const float* Wo = (const float*)d_in[10];
    const float* bo = (const float*)d_in[11];
    float* out = (float*)d_out;

    const size_t NX = (size_t)BB * SS * EMBD;
    const size_t NW = (size_t)EMBD * EMBD;
    bf16* Qw  = (bf16*)d_ws;        // [B,H,S,D], pre-scaled
    bf16* Kw  = Qw + NX;            // [B,H,S,D]
    bf16* Vw  = Kw + NX;            // [B,H,D,S]
    bf16* Aw  = Vw + NX;            // [B,S,E]
    bf16* xqb = Aw + NX;
    bf16* xkb = xqb + NX;
    bf16* xvb = xkb + NX;
    bf16* Wqb = xvb + NX;
    bf16* Wkb = Wqb + NW;
    bf16* Wvb = Wkb + NW;
    bf16* Wob = Wvb + NW;

    cvt_all<<<dim3(1024, 7), 256, 0, stream>>>(xq, xk, xv, Wq, Wk, Wv, Wo,
                                               xqb, xkb, xvb, Wqb, Wkb, Wvb,
                                               Wob);
    gemm_qkv<<<dim3(32, 8, 3), 256, 32768, stream>>>(
        xqb, xkb, xvb, Wqb, Wkb, Wvb, bq, bk, bv, Qw, Kw, Vw);
    attn_fwd<<<dim3(1024), 256, 0, stream>>>(Qw, Kw, Vw, Aw);
    gemm_out<<<dim3(64, 8), 256, 24576, stream>>>(Aw, Wob, bo, out);
}

// Round 3
// 224.092 us; speedup vs baseline: 1.1126x; 1.0227x over previous
//
#include <hip/hip_runtime.h>
#include <hip/hip_bf16.h>

// Problem: B=2, S=2048, EMB=1024, H=16, D=64.
// fp32 I/O; bf16 MFMA pipeline. V pre-transposed by QKV GEMM ([B,H,D,S]).
// Q pre-scaled by SCALE*log2(e) so attention softmax runs in exp2 domain.
#define BB   2
#define SS   2048
#define EMBD 1024
#define NH   16
#define HD   64
#define QSCALE 0.18033688011112042f  // 0.125 * log2(e)
#define NEG_BIG (-1e30f)

typedef __bf16 bf16;
typedef float  floatx4 __attribute__((ext_vector_type(4)));
typedef __bf16 bf16x4  __attribute__((ext_vector_type(4)));
typedef __bf16 bf16x8  __attribute__((ext_vector_type(8)));

typedef const __attribute__((address_space(1))) void* gas_ptr;
typedef __attribute__((address_space(3))) void*       las_ptr;

__device__ __forceinline__ void gl_lds16(const void* g, void* l) {
    __builtin_amdgcn_global_load_lds((gas_ptr)g, (las_ptr)l, 16, 0, 0);
}

__device__ __forceinline__ bf16x8 cvt8(const float* p) {
    bf16x8 o;
#pragma unroll
    for (int j = 0; j < 8; j++) o[j] = (bf16)p[j];
    return o;
}

// ---------------------------------------------------------------------------
// fp32 -> bf16 conversion for x tensors (4Mi els each) and W matrices (1Mi).
// ---------------------------------------------------------------------------
__global__ __launch_bounds__(256) void cvt_all(
    const float* __restrict__ xq, const float* __restrict__ xk,
    const float* __restrict__ xv, const float* __restrict__ Wq,
    const float* __restrict__ Wk, const float* __restrict__ Wv,
    const float* __restrict__ Wo, bf16* __restrict__ xqo,
    bf16* __restrict__ xko, bf16* __restrict__ xvo, bf16* __restrict__ Wqo,
    bf16* __restrict__ Wko, bf16* __restrict__ Wvo, bf16* __restrict__ Woo) {
    const int y = blockIdx.y;
    const float* src;
    bf16* dst;
    size_t n;
    const size_t NX = (size_t)BB * SS * EMBD;    // 4 Mi
    const size_t NW = (size_t)EMBD * EMBD;       // 1 Mi
    switch (y) {
        case 0: src = xq; dst = xqo; n = NX; break;
        case 1: src = xk; dst = xko; n = NX; break;
        case 2: src = xv; dst = xvo; n = NX; break;
        case 3: src = Wq; dst = Wqo; n = NW; break;
        case 4: src = Wk; dst = Wko; n = NW; break;
        case 5: src = Wv; dst = Wvo; n = NW; break;
        default: src = Wo; dst = Woo; n = NW; break;
    }
    const size_t stride = (size_t)gridDim.x * blockDim.x * 4;
    for (size_t i = ((size_t)blockIdx.x * blockDim.x + threadIdx.x) * 4;
         i < n; i += stride) {
        floatx4 v = *(const floatx4*)(src + i);
        bf16x4 o = {(bf16)v[0], (bf16)v[1], (bf16)v[2], (bf16)v[3]};
        *(bf16x4*)(dst + i) = o;
    }
}

// ---------------------------------------------------------------------------
// GEMM (unchanged): dynamic LDS, BK=64 staged as two packed 32-col halves,
// per-wave LDS repack epilogue.
// ---------------------------------------------------------------------------
extern __shared__ __align__(16) char smem[];

template <int MODE, int FM>
__device__ __forceinline__ void gemm_body(const bf16* __restrict__ A,
                                          const bf16* __restrict__ W,
                                          const float* __restrict__ bias,
                                          void* __restrict__ Ov,
                                          int mBase, int nBase, float oscale) {
    constexpr int BM = 32 * FM;
    constexpr int ABYTES = BM * 64 * 2;
    bf16* As = (bf16*)smem;
    bf16* Bs = (bf16*)(smem + ABYTES);

    const int t = threadIdx.x;
    const int l = t & 63, w = t >> 6;
    const int lm = l & 15, lq = l >> 4;
    const int K = 1024;
    const int wm = (w >> 1) * (16 * FM), wn = (w & 1) * 64;

    const floatx4 zero = {0.f, 0.f, 0.f, 0.f};
    floatx4 acc[FM][4];
#pragma unroll
    for (int i = 0; i < FM; i++)
#pragma unroll
        for (int j = 0; j < 4; j++) acc[i][j] = zero;

    for (int kb = 0; kb < K; kb += 64) {
        __syncthreads();
#pragma unroll
        for (int ia = 0; ia < FM; ia++) {
            int half = ia / (FM / 2 > 0 ? FM / 2 : 1);
            int rem  = (ia % (FM / 2 > 0 ? FM / 2 : 1)) * 256 + t;
            int row  = rem >> 2;
            int col  = half * 32 + (rem & 3) * 8;
            gl_lds16(A + (size_t)(mBase + row) * K + kb + col,
                     (char*)As + (ia * 256 + w * 64) * 16);
        }
#pragma unroll
        for (int i = 0; i < 4; i++) {
            int half = i >> 1;
            int rem  = (i & 1) * 256 + t;
            int row  = rem >> 2;
            int col  = half * 32 + (rem & 3) * 8;
            gl_lds16(W + (size_t)(nBase + row) * K + kb + col,
                     (char*)Bs + (i * 256 + w * 64) * 16);
        }
        __syncthreads();

#pragma unroll
        for (int half = 0; half < 2; half++) {
            const bf16* Ah = As + half * BM * 32;
            const bf16* Bh = Bs + half * 128 * 32;
            bf16x8 af[FM], bfv[4];
#pragma unroll
            for (int f = 0; f < FM; f++)
                af[f] = *(const bf16x8*)&Ah[(wm + f * 16 + lm) * 32 + lq * 8];
#pragma unroll
            for (int f = 0; f < 4; f++)
                bfv[f] = *(const bf16x8*)&Bh[(wn + f * 16 + lm) * 32 + lq * 8];
            if (MODE == 2) {
#pragma unroll
                for (int i = 0; i < 4; i++)
#pragma unroll
                    for (int j = 0; j < FM; j++)
                        acc[j][i] = __builtin_amdgcn_mfma_f32_16x16x32_bf16(
                            bfv[i], af[j], acc[j][i], 0, 0, 0);
            } else {
#pragma unroll
                for (int fm = 0; fm < FM; fm++)
#pragma unroll
                    for (int fn = 0; fn < 4; fn++)
                        acc[fm][fn] =
                            __builtin_amdgcn_mfma_f32_16x16x32_bf16(
                                af[fm], bfv[fn], acc[fm][fn], 0, 0, 0);
            }
        }
    }

    __syncthreads();
    float* rp = (float*)smem + w * (16 * 68);

    if (MODE != 2) {
        float bvv[4];
#pragma unroll
        for (int fn = 0; fn < 4; fn++)
            bvv[fn] = bias[nBase + wn + fn * 16 + lm];
#pragma unroll
        for (int fm = 0; fm < FM; fm++) {
#pragma unroll
            for (int fn = 0; fn < 4; fn++)
#pragma unroll
                for (int r = 0; r < 4; r++)
                    rp[(lq * 4 + r) * 68 + fn * 16 + lm] =
                        (acc[fm][fn][r] + bvv[fn]) * oscale;
            if (MODE == 0) {
                int row2 = l >> 3, col8 = l & 7;
                int h = (nBase + wn) >> 6;
#pragma unroll
                for (int p = 0; p < 2; p++) {
                    int row = p * 8 + row2;
                    int m = mBase + wm + fm * 16 + row;
                    int b = m >> 11, s = m & 2047;
                    bf16x8 o = cvt8(&rp[row * 68 + col8 * 8]);
                    *(bf16x8*)((bf16*)Ov +
                               (((size_t)(b * NH + h)) * SS + s) * HD +
                               col8 * 8) = o;
                }
            } else {
                int c4 = l & 15;
#pragma unroll
                for (int p = 0; p < 4; p++) {
                    int row = p * 4 + (l >> 4);
                    int m = mBase + wm + fm * 16 + row;
                    floatx4 o = *(const floatx4*)&rp[row * 68 + c4 * 4];
                    *(floatx4*)((float*)Ov + (size_t)m * EMBD + nBase + wn +
                                c4 * 4) = o;
                }
            }
        }
    } else {
        const int b = (mBase + wm) >> 11;
        const int sbase = (mBase + wm) & 2047;
#pragma unroll
        for (int i = 0; i < 4; i++) {
            float bv[4];
#pragma unroll
            for (int r = 0; r < 4; r++)
                bv[r] = bias[nBase + wn + i * 16 + lq * 4 + r];
#pragma unroll
            for (int j = 0; j < FM; j++)
#pragma unroll
                for (int r = 0; r < 4; r++)
                    rp[(lq * 4 + r) * 68 + j * 16 + lm] =
                        acc[j][i][r] + bv[r];
            int row2 = l >> 3, col8 = l & 7;
#pragma unroll
            for (int p = 0; p < 2; p++) {
                int row = p * 8 + row2;
                int n = nBase + wn + i * 16 + row;
                int h = n >> 6, d = n & 63;
                bf16x8 o = cvt8(&rp[row * 68 + col8 * 8]);
                *(bf16x8*)((bf16*)Ov +
                           ((size_t)(b * NH + h) * HD + d) * SS + sbase +
                           col8 * 8) = o;
            }
        }
    }
}

__global__ __launch_bounds__(256, 4) void gemm_qkv(
    const bf16* __restrict__ xq, const bf16* __restrict__ xk,
    const bf16* __restrict__ xv, const bf16* __restrict__ Wq,
    const bf16* __restrict__ Wk, const bf16* __restrict__ Wv,
    const float* __restrict__ bq, const float* __restrict__ bk,
    const float* __restrict__ bv, bf16* __restrict__ Qo,
    bf16* __restrict__ Ko, bf16* __restrict__ Vo) {
    const int z = blockIdx.z;
    const int mB = blockIdx.x * 128, nB = blockIdx.y * 128;
    if (z == 0)
        gemm_body<0, 4>(xq, Wq, bq, Qo, mB, nB, QSCALE);
    else if (z == 1)
        gemm_body<0, 4>(xk, Wk, bk, Ko, mB, nB, 1.0f);
    else
        gemm_body<2, 4>(xv, Wv, bv, Vo, mB, nB, 1.0f);
}

__global__ __launch_bounds__(256, 4) void gemm_out(
    const bf16* __restrict__ A, const bf16* __restrict__ W,
    const float* __restrict__ bias, float* __restrict__ O) {
    gemm_body<1, 2>(A, W, bias, O, blockIdx.x * 64, blockIdx.y * 128, 1.0f);
}

// ---------------------------------------------------------------------------
// Flash attention v4, KT=64 double-buffered via global_load_lds:
//  - R2's pathology was register-spill HBM traffic (WRITE 52 MB vs 8.4 real):
//    kreg/vreg prefetch (32 VGPR) + sc[8] (32) + od (16) + qa (8) > 84 regs.
//  - Fix: no register staging. K/V staged direct-to-LDS with gl_lds16 using
//    PRE-SWIZZLED per-lane GLOBAL addresses (LDS dest must be lane-linear);
//    read-side XOR swizzles identical to the R2-validated ones.
//  - KT=64, double-buffered: Ks[2][64][64] + VT[2][64][64] + Ps[4][16*64]
//    = 40 KB -> 4 blocks/CU. sc shrinks to 4 regs-of-4. ONE __syncthreads
//    per chunk (implicit vmcnt(0) drains prefetch; write buf != read buf).
//  - Live set ~70 VGPR -> no spills.
// ---------------------------------------------------------------------------
__global__ __launch_bounds__(256, 3) void attn_fwd(
    const bf16* __restrict__ Qg, const bf16* __restrict__ Kg,
    const bf16* __restrict__ Vtg, bf16* __restrict__ Oatt) {
    __shared__ __align__(16) bf16 Ksb[2 * 64 * 64];  // [buf][key][d], swz src
    __shared__ __align__(16) bf16 VTb[2 * 64 * 64];  // [buf][d][key], swz src
    __shared__ __align__(16) bf16 Ps[4][16 * 64];    // per-wave P, swizzled

    const int t = threadIdx.x;
    const int l = t & 63, w = t >> 6;
    const int lm = l & 15, lq = l >> 4;
    const int m7 = lm & 7;
    const int x = blockIdx.x;
    const int i5 = x >> 5;                      // 0..31
    const int gq = i5 >> 3, jq = i5 & 7;
    const int qt = (gq == 0) ? jq
                 : (gq == 1) ? 15 - jq
                 : (gq == 2) ? 16 + jq
                             : 31 - jq;        // balanced bijection
    const int bh = (((x >> 3) & 3) << 3) | (x & 7);  // XCD-pinned head
    const size_t kbase = (size_t)bh * SS * HD;
    const size_t vbase = (size_t)bh * HD * SS;
    const int b = bh >> 4, h = bh & 15;
    const floatx4 zero = {0.f, 0.f, 0.f, 0.f};

    // Per-thread pre-swizzled global staging addresses.
    // LDS linear slot for thread t, instr i: off = (i*256+t)*16B
    //   K: row = i*32 + (t>>3)   (row&7 invariant in i), slot = t&7
    //   V: d   = i*32 + (t>>3), slot = t&7
    // Source column so that LDS[row][slot] holds global col (slot^(row&7)):
    const int trow = t >> 3, tsl = t & 7;
    const int cswz = ((tsl ^ (trow & 7)) << 3);      // element offset
    const bf16* kgp = Kg + kbase + (size_t)trow * HD + cswz;
    const bf16* vgp = Vtg + vbase + (size_t)trow * SS + cswz;
    bf16* ksd = Ksb + t * 8;     // 16B per thread, lane-linear per wave
    bf16* vtd = VTb + t * 8;

    bf16x8 qa0, qa1;
    {
        const bf16* qp =
            Qg + kbase + (size_t)(qt * 64 + w * 16 + lm) * HD + lq * 8;
        qa0 = *(const bf16x8*)qp;
        qa1 = *(const bf16x8*)(qp + 32);
    }

    float m_i = NEG_BIG, l_i = 0.f;            // stats for q = lm (this wave)
    floatx4 od[4];
#pragma unroll
    for (int dt = 0; dt < 4; dt++) od[dt] = zero;

    const int qglob = qt * 64 + w * 16 + lm;

    // Prologue: stage chunk 0 into buffer 0.
    gl_lds16(kgp, ksd);
    gl_lds16(kgp + 2048, ksd + 2048);          // +32 K rows
    gl_lds16(vgp, vtd);
    gl_lds16(vgp + 32 * SS, vtd + 2048);       // +32 d rows
    __syncthreads();

    for (int kt = 0; kt <= qt; ++kt) {
        const int cur = kt & 1;
        const bf16* Kc = Ksb + cur * 4096;
        const bf16* Vc = VTb + cur * 4096;
        if (kt < qt) {                          // prefetch chunk kt+1
            const bf16* kp = kgp + (size_t)(kt + 1) * 4096;  // 64 rows * 64
            const bf16* vp = vgp + (size_t)(kt + 1) * 64;    // 64 keys
            bf16* kn = ksd + (cur ^ 1) * 4096;
            bf16* vn = vtd + (cur ^ 1) * 4096;
            gl_lds16(kp, kn);
            gl_lds16(kp + 2048, kn + 2048);
            gl_lds16(vp, vn);
            gl_lds16(vp + 32 * SS, vn + 2048);
        }

        // S^T[key][q], 4 subtiles of 16 keys (64 total)
        floatx4 sc[4];
#pragma unroll
        for (int j0 = 0; j0 < 4; j0++) {
            int rowK = j0 * 16 + lm;
            bf16x8 k0 = *(const bf16x8*)&Kc[rowK * 64 + ((lq ^ m7) << 3)];
            bf16x8 k1 =
                *(const bf16x8*)&Kc[rowK * 64 + (((4 + lq) ^ m7) << 3)];
            floatx4 z = zero;
            z = __builtin_amdgcn_mfma_f32_16x16x32_bf16(k0, qa0, z, 0, 0, 0);
            z = __builtin_amdgcn_mfma_f32_16x16x32_bf16(k1, qa1, z, 0, 0, 0);
            sc[j0] = z;
        }
        if (kt == qt) {  // causal mask: diagonal chunk
#pragma unroll
            for (int j0 = 0; j0 < 4; j0++)
#pragma unroll
                for (int r = 0; r < 4; r++) {
                    int key = kt * 64 + j0 * 16 + lq * 4 + r;
                    if (key > qglob) sc[j0][r] = NEG_BIG;
                }
        }
        // Online softmax (exp2 domain); all 16 regs belong to q = lm.
        float m4[4];
#pragma unroll
        for (int a = 0; a < 4; a++)
            m4[a] = fmaxf(fmaxf(sc[a][0], sc[a][1]),
                          fmaxf(sc[a][2], sc[a][3]));
        float mt = fmaxf(fmaxf(m4[0], m4[1]), fmaxf(m4[2], m4[3]));
        mt = fmaxf(mt, __shfl_xor(mt, 16));
        mt = fmaxf(mt, __shfl_xor(mt, 32));
        float mnew = fmaxf(m_i, mt);
        float alpha = __builtin_amdgcn_exp2f(m_i - mnew);
        m_i = mnew;
        float psa0 = 0.f, psa1 = 0.f, psa2 = 0.f, psa3 = 0.f;
#pragma unroll
        for (int j0 = 0; j0 < 4; j0++) {
            float p0 = __builtin_amdgcn_exp2f(sc[j0][0] - mnew);
            float p1 = __builtin_amdgcn_exp2f(sc[j0][1] - mnew);
            float p2 = __builtin_amdgcn_exp2f(sc[j0][2] - mnew);
            float p3 = __builtin_amdgcn_exp2f(sc[j0][3] - mnew);
            sc[j0][0] = p0; sc[j0][1] = p1;
            sc[j0][2] = p2; sc[j0][3] = p3;
            psa0 += p0; psa1 += p1; psa2 += p2; psa3 += p3;
        }
        float ps = (psa0 + psa1) + (psa2 + psa3);
        ps += __shfl_xor(ps, 16);
        ps += __shfl_xor(ps, 32);
        l_i = l_i * alpha + ps;
        float a0 = __shfl(alpha, lq * 4 + 0);
        float a1 = __shfl(alpha, lq * 4 + 1);
        float a2 = __shfl(alpha, lq * 4 + 2);
        float a3 = __shfl(alpha, lq * 4 + 3);
#pragma unroll
        for (int dt = 0; dt < 4; dt++) {
            od[dt][0] *= a0;
            od[dt][1] *= a1;
            od[dt][2] *= a2;
            od[dt][3] *= a3;
        }
        // P -> LDS (bf16), then PV over 64 keys = 2 k-steps.
#pragma unroll
        for (int j0l = 0; j0l < 4; j0l++) {
            floatx4 s4 = sc[j0l];
            bf16x4 pk = {(bf16)s4[0], (bf16)s4[1], (bf16)s4[2], (bf16)s4[3]};
            *(bf16x4*)&Ps[w][lm * 64 + ((j0l * 16 + lq * 4) ^ (m7 * 8))] = pk;
        }
        bf16x8 pa0 = *(const bf16x8*)&Ps[w][lm * 64 + ((lq * 8) ^ (m7 * 8))];
        bf16x8 pa1 =
            *(const bf16x8*)&Ps[w][lm * 64 + ((32 + lq * 8) ^ (m7 * 8))];
#pragma unroll
        for (int dt = 0; dt < 4; dt++) {
            int rowD = dt * 16 + lm;
            bf16x8 v0 = *(const bf16x8*)&Vc[rowD * 64 + ((lq ^ m7) << 3)];
            od[dt] = __builtin_amdgcn_mfma_f32_16x16x32_bf16(pa0, v0, od[dt],
                                                             0, 0, 0);
            bf16x8 v1 =
                *(const bf16x8*)&Vc[rowD * 64 + (((4 + lq) ^ m7) << 3)];
            od[dt] = __builtin_amdgcn_mfma_f32_16x16x32_bf16(pa1, v1, od[dt],
                                                             0, 0, 0);
        }
        __syncthreads();   // drains prefetch (vmcnt 0) + all reads of cur
    }

    float linv = 1.0f / l_i;
    float lr0 = __shfl(linv, lq * 4 + 0);
    float lr1 = __shfl(linv, lq * 4 + 1);
    float lr2 = __shfl(linv, lq * 4 + 2);
    float lr3 = __shfl(linv, lq * 4 + 3);
    float lr[4] = {lr0, lr1, lr2, lr3};
#pragma unroll
    for (int dt = 0; dt < 4; dt++) {
#pragma unroll
        for (int r = 0; r < 4; r++) {
            int s = qt * 64 + w * 16 + lq * 4 + r;
            float v = od[dt][r] * lr[r];
            Oatt[((size_t)(b * SS + s)) * EMBD + h * HD + dt * 16 + lm] =
                (bf16)v;
        }
    }
}

// ---------------------------------------------------------------------------
extern "C" void kernel_launch(void* const* d_in, const int* in_sizes, int n_in,
                              void* d_out, int out_size, void* d_ws,
                              size_t ws_size, hipStream_t stream) {
    const float* xq = (const float*)d_in[0];
    const float* xk = (const float*)d_in[1];
    const float* xv = (const float*)d_in[2];
    // d_in[3] = causal mask — hard-coded
    const float* Wq = (const float*)d_in[4];
    const float* bq = (const float*)d_in[5];
    const float* Wk = (const float*)d_in[6];
    const float* bk = (const float*)d_in[7];
    const float* Wv = (const float*)d_in[8];
    const float* bv = (const float*)d_in[9];
    const float* Wo = (const float*)d_in[10];
    const float* bo = (const float*)d_in[11];
    float* out = (float*)d_out;

    const size_t NX = (size_t)BB * SS * EMBD;
    const size_t NW = (size_t)EMBD * EMBD;
    bf16* Qw  = (bf16*)d_ws;        // [B,H,S,D], pre-scaled
    bf16* Kw  = Qw + NX;            // [B,H,S,D]
    bf16* Vw  = Kw + NX;            // [B,H,D,S]
    bf16* Aw  = Vw + NX;            // [B,S,E]
    bf16* xqb = Aw + NX;
    bf16* xkb = xqb + NX;
    bf16* xvb = xkb + NX;
    bf16* Wqb = xvb + NX;
    bf16* Wkb = Wqb + NW;
    bf16* Wvb = Wkb + NW;
    bf16* Wob = Wvb + NW;

    cvt_all<<<dim3(1024, 7), 256, 0, stream>>>(xq, xk, xv, Wq, Wk, Wv, Wo,
                                               xqb, xkb, xvb, Wqb, Wkb, Wvb,
                                               Wob);
    gemm_qkv<<<dim3(32, 8, 3), 256, 32768, stream>>>(
        xqb, xkb, xvb, Wqb, Wkb, Wvb, bq, bk, bv, Qw, Kw, Vw);
    attn_fwd<<<dim3(1024), 256, 0, stream>>>(Qw, Kw, Vw, Aw);
    gemm_out<<<dim3(64, 8), 256, 24576, stream>>>(Aw, Wob, bo, out);
}